// Round 14
// baseline (338.385 us; speedup 1.0000x reference)
//
#include <hip/hip_runtime.h>
#include <hip/hip_bf16.h>
#include <stdint.h>
#include <math.h>

typedef unsigned short u16;
typedef __attribute__((ext_vector_type(8))) __bf16 bf16x8;
typedef __attribute__((ext_vector_type(4))) float f32x4;

#define LOG2E 1.44269504088896340736f
// no FIXED_M: softmax scale 2^-M cancels exactly between O and L.

__device__ inline u16 f2bf(float f){
  uint32_t u = __float_as_uint(f);
  u += 0x7FFFu + ((u >> 16) & 1u);   // round-to-nearest-even
  return (u16)(u >> 16);
}
__device__ inline float bf2f(u16 v){
  return __uint_as_float(((uint32_t)v) << 16);
}

// ---------------------------------------------------------------------------
// Kernel C: W[768][64] x3 (fp32) -> wtf in EXACT MFMA B-fragment order.
// Folds (1/8)*log2(e) into Wq so scores are in log2 domain.
// Also zeroes the 128 flash combine-tickets (workspace is poisoned by the
// harness each iteration; wt is stream-ordered before flash).
// ---------------------------------------------------------------------------
__global__ __launch_bounds__(256) void wt_kernel(const float* __restrict__ Wq,
                                                 const float* __restrict__ Wk,
                                                 const float* __restrict__ Wv,
                                                 u16* __restrict__ wtf,
                                                 int* __restrict__ tick){
  if (blockIdx.x == 0 && threadIdx.x < 128) tick[threadIdx.x] = 0;
  int idx = blockIdx.x * 256 + threadIdx.x;
  if (idx >= 192 * 768) return;
  int n = idx / 768, c = idx - n * 768;
  int h = n & 63;
  const float* W = (n < 64) ? Wq : ((n < 128) ? Wk : Wv);
  float v = W[c * 64 + h];
  if (n < 64) v *= 0.125f * LOG2E;
  int f = n >> 4, n16 = n & 15;
  int kstep = c >> 5, quad = (c >> 3) & 3, j = c & 7;
  wtf[(size_t)((f * 24 + kstep) * 64 + quad * 16 + n16) * 8 + j] = f2bf(v);
}

// ---------------------------------------------------------------------------
// Kernel A v6: projection GEMM, M=16384, N=192, K=768. 1024 blocks x 256 thr.
// BM=16 (24KB LDS, 4 blocks/CU), waves split N (3 frags each), chunked
// pipelined staging (4 chunks of 6 k-steps, loads fly over compute).
// Epilogue via LDS -> all global stores coalesced 16B/lane.
// ksf: [b][kt][f][half][lane(quad,n16)][j] = K[kt*64+f*16+n16][half*32+quad*8+j]
// vtf: [b][kt][f][half][lane(quad,n16)][j] = V[kt*64+half*32+quad*8+j][f*16+n16]
// ---------------------------------------------------------------------------
__global__ __launch_bounds__(256) void proj_kernel(const float* __restrict__ x,
                                                   const u16* __restrict__ wtf,
                                                   u16* __restrict__ qs,
                                                   u16* __restrict__ ksf,
                                                   u16* __restrict__ vtf){
  __shared__ u16 At[24 * 64 * 8];   // 24KB; reused as epilogue buffers
  const int tid = threadIdx.x;
  const int w = tid >> 6, lane = tid & 63;
  const int n16 = lane & 15, quad = lane >> 4;
  const int rt = blockIdx.x * 16;
  const float* xb = x + (size_t)rt * 768;

  float4 tr0, tr1, tr2;
#define LOADR(c) {                                                           \
    int jj0 = tid,       r0 = jj0 / 48, q0 = jj0 - r0 * 48;                  \
    int jj1 = 256 + tid, r1 = jj1 / 48, q1 = jj1 - r1 * 48;                  \
    int jj2 = 512 + tid, r2 = jj2 / 48, q2 = jj2 - r2 * 48;                  \
    tr0 = *(const float4*)(xb + ((size_t)r0 * 192 + (c) * 48 + q0) * 4);     \
    tr1 = *(const float4*)(xb + ((size_t)r1 * 192 + (c) * 48 + q1) * 4);     \
    tr2 = *(const float4*)(xb + ((size_t)r2 * 192 + (c) * 48 + q2) * 4);     \
  }
#define WR1(c, jj, t) {                                                      \
    int rr = (jj) / 48, ql = (jj) - rr * 48;                                 \
    int ksn = (c) * 6 + (ql >> 3), qd = (ql >> 1) & 3, j0 = (ql & 1) * 4;    \
    int idx = ((ksn * 64 + qd * 16 + rr) * 8 + j0) ^ ((ksn & 7) << 3);       \
    union { ushort4 s; u16 e[4]; } pk;                                       \
    pk.e[0] = f2bf(t.x); pk.e[1] = f2bf(t.y);                                \
    pk.e[2] = f2bf(t.z); pk.e[3] = f2bf(t.w);                                \
    *(ushort4*)&At[idx] = pk.s;                                              \
  }
#define WRITES(c) { WR1(c, tid, tr0); WR1(c, 256 + tid, tr1); WR1(c, 512 + tid, tr2); }
#define COMPUTE(c) {                                                         \
    _Pragma("unroll") for (int kk = 0; kk < 6; ++kk){                        \
      int kst = (c) * 6 + kk;                                                \
      int sw = (kst & 7) << 3;                                               \
      bf16x8 a = *(const bf16x8*)&At[((kst * 64 + lane) * 8) ^ sw];          \
      _Pragma("unroll") for (int j = 0; j < 3; ++j){                         \
        bf16x8 bfr = *(const bf16x8*)(wtf + (size_t)(((3 * w + j) * 24 + kst) * 64 + lane) * 8); \
        acc[j] = __builtin_amdgcn_mfma_f32_16x16x32_bf16(a, bfr, acc[j], 0, 0, 0); \
      }                                                                      \
    }                                                                        \
  }

  const f32x4 fz = {0.f, 0.f, 0.f, 0.f};
  f32x4 acc[3];
#pragma unroll
  for (int j = 0; j < 3; ++j) acc[j] = fz;

  const int ch0 = blockIdx.x & 3;          // rotation staggers block phases
  const int ch1 = (ch0 + 1) & 3, ch2 = (ch0 + 2) & 3, ch3 = (ch0 + 3) & 3;

  LOADR(ch0); WRITES(ch0);
  __syncthreads();
  LOADR(ch1);            // flies over COMPUTE(ch0)
  COMPUTE(ch0);
  WRITES(ch1);
  __syncthreads();
  LOADR(ch2);
  COMPUTE(ch1);
  WRITES(ch2);
  __syncthreads();
  LOADR(ch3);
  COMPUTE(ch2);
  WRITES(ch3);
  __syncthreads();
  COMPUTE(ch3);
  __syncthreads();       // all waves done reading At -> safe to reuse
#undef LOADR
#undef WR1
#undef WRITES
#undef COMPUTE

  // C -> LDS transpose: EQ @0 [16][72], EK @1152 [16][72], EV @2304 [64][24]
#pragma unroll
  for (int j = 0; j < 3; ++j){
    const int F = 3 * w + j;
    const int s = F >> 2, c0 = (F & 3) * 16;
#pragma unroll
    for (int r = 0; r < 4; ++r){
      u16 val = f2bf(acc[j][r]);
      int row = quad * 4 + r;
      if (s < 2) At[s * 1152 + row * 72 + c0 + n16] = val;
      else       At[2304 + (c0 + n16) * 24 + row]   = val;
    }
  }
  __syncthreads();

  const int bb = rt >> 12, t0 = rt & 4095;
  const int kt = t0 >> 6;
  const int fk = (t0 >> 4) & 3;
  const int half0 = (t0 >> 5) & 1;
  const int qhalf = (t0 >> 4) & 1;
  if (tid < 128){
    int row = tid >> 3, hc = tid & 7;
    uint4 qv = *(const uint4*)&At[row * 72 + hc * 8];
    *(uint4*)(qs + (size_t)(rt + row) * 64 + hc * 8) = qv;
  } else {
    int tt = tid - 128;
    int half = tt >> 6, l2 = tt & 63;
    int nn = l2 & 15, qq = l2 >> 4;
    uint4 kv = *(const uint4*)&At[1152 + nn * 72 + half * 32 + qq * 8];
    size_t off = ((((size_t)(bb * 64 + kt) * 4 + fk) * 2 + half) * 64 + l2) * 8;
    *(uint4*)(ksf + off) = kv;
  }
  if (tid < 128){
    int f = tid >> 5, idx5 = tid & 31;
    int qsel = idx5 >> 4, nn = idx5 & 15;
    int h = f * 16 + nn;
    uint4 vv = *(const uint4*)&At[2304 + h * 24 + qsel * 8];
    int lane2 = (2 * qhalf + qsel) * 16 + nn;
    size_t off = ((((size_t)(bb * 64 + kt) * 4 + f) * 2 + half0) * 64 + lane2) * 8;
    *(uint4*)(vtf + off) = vv;
  }
}

// ---------------------------------------------------------------------------
// Kernel B v11: split-K causal flash (v10 body: QBLK=128, dense balanced
// grid, T14 prefetch) + INLINE COMBINE via atomic ticket: after the partial
// epilogue, __threadfence(); atomicAdd(tick[bq]); the LAST-arriving block
// for each (b,qt) re-reads all partials (L1-miss -> L2, write-through-safe)
// and writes the final output. Removes the combine dispatch + its gap, and
// overlaps combining with still-running flash blocks.
// Dense grid: 1088 blocks, nt=4 class (1024) + nt=2 class (64).
// ---------------------------------------------------------------------------
__global__ __launch_bounds__(256) void flash_part(const u16* __restrict__ qs,
                                                  const u16* __restrict__ ksf,
                                                  const u16* __restrict__ vtf,
                                                  u16* __restrict__ Opart,
                                                  float* __restrict__ ml,
                                                  float* __restrict__ out,
                                                  int* __restrict__ tick){
  const int gid = blockIdx.x;
  int b, qt, ck, nt;
  if (gid < 1024){                       // nt=4 class
    b = gid >> 8;
    int r = gid & 255;
    int m = (int)sqrtf((float)r);
    if (m * m > r) --m;
    if ((m + 1) * (m + 1) <= r) ++m;
    int d = r - m * m;
    if (d < m){ qt = 2 * m;     ck = d;     }
    else      { qt = 2 * m + 1; ck = d - m; }
    nt = 4;
  } else {                               // nt=2 class (qt even, last chunk)
    int t = gid - 1024;
    b = t >> 4;
    int m = t & 15;
    qt = 2 * m; ck = m; nt = 2;
  }
  const int kt0 = ck * 4;

  __shared__ u16 Kb[4096];               // 8KB, frag-linear
  __shared__ u16 Vb[4096];
  __shared__ u16 Ps[128 * 72];           // per-wave P staging, 18KB
  __shared__ int lastflag;
  const int tid = threadIdx.x;
  const int w = tid >> 6, lane = tid & 63;
  const int n16 = lane & 15, quad = lane >> 4;

  const u16* qb  = qs  + (size_t)b * 262144;
  const u16* kpg = ksf + (size_t)b * 262144 + (size_t)kt0 * 4096;
  const u16* vpg = vtf + (size_t)b * 262144 + (size_t)kt0 * 4096;

  // Q frags: qA[m][kh]
  bf16x8 qA[2][2];
#pragma unroll
  for (int m = 0; m < 2; ++m){
    const size_t qrow = (size_t)(qt * 128 + w * 32 + m * 16 + n16) * 64;
    qA[m][0] = *(const bf16x8*)(qb + qrow + quad * 8);
    qA[m][1] = *(const bf16x8*)(qb + qrow + 32 + quad * 8);
  }

  const f32x4 fz = {0.f, 0.f, 0.f, 0.f};
  f32x4 O[2][4];
  float rs[2][4];
#pragma unroll
  for (int m = 0; m < 2; ++m)
#pragma unroll
    for (int f = 0; f < 4; ++f){ O[m][f] = fz; rs[m][f] = 0.f; }

  // T14 staging registers: thread tid owns bytes [tid*32, +32) of each tile.
  uint4 rk0, rk1, rv0, rv1;
#define LOADR(ti)                                                            \
  {                                                                          \
    const u16* kg = kpg + (size_t)(ti) * 4096 + tid * 16;                    \
    const u16* vg = vpg + (size_t)(ti) * 4096 + tid * 16;                    \
    rk0 = *(const uint4*)kg;  rk1 = *(const uint4*)(kg + 8);                 \
    rv0 = *(const uint4*)vg;  rv1 = *(const uint4*)(vg + 8);                 \
  }
#define WRITES()                                                             \
  {                                                                          \
    *(uint4*)&Kb[tid * 16] = rk0;  *(uint4*)&Kb[tid * 16 + 8] = rk1;         \
    *(uint4*)&Vb[tid * 16] = rv0;  *(uint4*)&Vb[tid * 16 + 8] = rv1;         \
  }

  LOADR(0);
  WRITES();
  __syncthreads();                       // tile 0 ready

  for (int it = 0; it < nt; ++it){
    const int kt = kt0 + it;
    if (it + 1 < nt) LOADR(it + 1);      // flies over this iter's compute

    f32x4 S[2][4];
#pragma unroll
    for (int f = 0; f < 4; ++f){
      bf16x8 k0 = *(const bf16x8*)&Kb[(f * 2 + 0) * 512 + lane * 8];
      bf16x8 k1 = *(const bf16x8*)&Kb[(f * 2 + 1) * 512 + lane * 8];
#pragma unroll
      for (int m = 0; m < 2; ++m){
        f32x4 s = fz;
        s = __builtin_amdgcn_mfma_f32_16x16x32_bf16(qA[m][0], k0, s, 0, 0, 0);
        s = __builtin_amdgcn_mfma_f32_16x16x32_bf16(qA[m][1], k1, s, 0, 0, 0);
        S[m][f] = s;
      }
    }

    if (kt >= 2 * qt){
#pragma unroll
      for (int m = 0; m < 2; ++m)
#pragma unroll
        for (int f = 0; f < 4; ++f)
#pragma unroll
          for (int r = 0; r < 4; ++r){
            int col = kt * 64 + f * 16 + n16;
            int row = qt * 128 + w * 32 + m * 16 + quad * 4 + r;
            if (col > row) S[m][f][r] = -1e30f;
          }
    }

#pragma unroll
    for (int m = 0; m < 2; ++m)
#pragma unroll
      for (int f = 0; f < 4; ++f)
#pragma unroll
        for (int r = 0; r < 4; ++r){
          float p = __builtin_amdgcn_exp2f(S[m][f][r]);
          S[m][f][r] = p;
          rs[m][r] += p;
        }

#pragma unroll
    for (int m = 0; m < 2; ++m)
#pragma unroll
      for (int f = 0; f < 4; ++f){
        u16* p = &Ps[(w * 32 + m * 16 + quad * 4) * 72 + f * 16 + n16];
        p[0]   = f2bf(S[m][f][0]);
        p[72]  = f2bf(S[m][f][1]);
        p[144] = f2bf(S[m][f][2]);
        p[216] = f2bf(S[m][f][3]);
      }
    bf16x8 pA[2][2];
#pragma unroll
    for (int m = 0; m < 2; ++m){
      pA[m][0] = *(const bf16x8*)&Ps[(w * 32 + m * 16 + n16) * 72 + quad * 8];
      pA[m][1] = *(const bf16x8*)&Ps[(w * 32 + m * 16 + n16) * 72 + 32 + quad * 8];
    }

#pragma unroll
    for (int f = 0; f < 4; ++f){
      bf16x8 v0 = *(const bf16x8*)&Vb[(f * 2 + 0) * 512 + lane * 8];
      bf16x8 v1 = *(const bf16x8*)&Vb[(f * 2 + 1) * 512 + lane * 8];
#pragma unroll
      for (int m = 0; m < 2; ++m){
        O[m][f] = __builtin_amdgcn_mfma_f32_16x16x32_bf16(pA[m][0], v0, O[m][f], 0, 0, 0);
        O[m][f] = __builtin_amdgcn_mfma_f32_16x16x32_bf16(pA[m][1], v1, O[m][f], 0, 0, 0);
      }
    }

    if (it + 1 < nt){
      __syncthreads();                   // all waves done reading tile it
      WRITES();                          // staged regs -> LDS (tile it+1)
      __syncthreads();                   // tile it+1 visible
    }
  }
#undef LOADR
#undef WRITES

  // one-time row-sum reduction across the 16 n16 lanes
#pragma unroll
  for (int m = 0; m < 2; ++m)
#pragma unroll
    for (int r = 0; r < 4; ++r){
#pragma unroll
      for (int off = 1; off < 16; off <<= 1)
        rs[m][r] += __shfl_xor(rs[m][r], off, 16);
    }

  // epilogue: unnormalized partial O (bf16) + l per row, indexed by dense gid
  const size_t oidx = (size_t)gid * 8192;
#pragma unroll
  for (int m = 0; m < 2; ++m)
#pragma unroll
    for (int f = 0; f < 4; ++f)
#pragma unroll
      for (int r = 0; r < 4; ++r){
        int row_local = w * 32 + m * 16 + quad * 4 + r;
        Opart[oidx + (size_t)row_local * 64 + f * 16 + n16] = f2bf(O[m][f][r]);
      }
  if (n16 == 0){
    float* lp = ml + (size_t)gid * 128;
#pragma unroll
    for (int m = 0; m < 2; ++m)
#pragma unroll
      for (int r = 0; r < 4; ++r)
        lp[w * 32 + m * 16 + quad * 4 + r] = rs[m][r];
  }

  // ---- inline combine: last-arriving block for this (b,qt) finishes it ----
  const int mq = qt >> 1;
  const int nc4 = (qt & 1) ? (mq + 1) : mq;
  const int Fq = (qt & 1) ? (mq * mq + mq) : (mq * mq);
  const int total = nc4 + ((qt & 1) ? 0 : 1);
  const int bq = b * 32 + qt;

  __threadfence();                       // release: partials visible in L2
  if (tid == 0)
    lastflag = (atomicAdd(&tick[bq], 1) == total - 1);
  __syncthreads();
  if (!lastflag) return;
  __threadfence();                       // acquire side

#pragma unroll
  for (int u = 0; u < 8; ++u){
    const int e = (u * 256 + tid) * 4;   // element in [0, 8192)
    const int row = e >> 6;
    float L = 0.f, a0 = 0.f, a1 = 0.f, a2 = 0.f, a3 = 0.f;
    for (int j = 0; j < nc4; ++j){
      int p = b * 256 + Fq + j;
      L += ml[(size_t)p * 128 + row];
      const u16* q = Opart + (size_t)p * 8192 + e;
      uint2 d = *(const uint2*)q;
      a0 += bf2f((u16)(d.x & 0xffffu));
      a1 += bf2f((u16)(d.x >> 16));
      a2 += bf2f((u16)(d.y & 0xffffu));
      a3 += bf2f((u16)(d.y >> 16));
    }
    if (!(qt & 1)){
      int p = 1024 + b * 16 + mq;
      L += ml[(size_t)p * 128 + row];
      const u16* q = Opart + (size_t)p * 8192 + e;
      uint2 d = *(const uint2*)q;
      a0 += bf2f((u16)(d.x & 0xffffu));
      a1 += bf2f((u16)(d.x >> 16));
      a2 += bf2f((u16)(d.y & 0xffffu));
      a3 += bf2f((u16)(d.y >> 16));
    }
    const float invL = 1.0f / L;
    float4 v = {a0 * invL, a1 * invL, a2 * invL, a3 * invL};
    *(float4*)(out + (size_t)bq * 8192 + e) = v;
  }
}

// ---------------------------------------------------------------------------
extern "C" void kernel_launch(void* const* d_in, const int* in_sizes, int n_in,
                              void* d_out, int out_size, void* d_ws, size_t ws_size,
                              hipStream_t stream){
  const float* x  = (const float*)d_in[0];
  const float* Wq = (const float*)d_in[1];
  const float* Wk = (const float*)d_in[2];
  const float* Wv = (const float*)d_in[3];
  float* out = (float*)d_out;

  // ws (u16 elems): qs|ksf|vtf (each 16384*64) | wtf (192*768)
  //                 | Opart (1088*8192) | ml (1088*128 f32) | tick (128 i32)
  u16* qs  = (u16*)d_ws;
  u16* ksf = qs  + (size_t)16384 * 64;
  u16* vtf = ksf + (size_t)16384 * 64;
  u16* wtf = vtf + (size_t)16384 * 64;
  u16* Opart = wtf + (size_t)192 * 768;
  float* ml = (float*)(Opart + (size_t)1088 * 8192);
  int* tick = (int*)(ml + (size_t)1088 * 128);

  wt_kernel<<<576, 256, 0, stream>>>(Wq, Wk, Wv, wtf, tick);
  proj_kernel<<<1024, 256, 0, stream>>>(x, wtf, qs, ksf, vtf);
  flash_part<<<1088, 256, 0, stream>>>(qs, ksf, vtf, Opart, ml, out, tick);
}

// Round 15
// 202.173 us; speedup vs baseline: 1.6737x; 1.6737x over previous
//
#include <hip/hip_runtime.h>
#include <hip/hip_bf16.h>
#include <stdint.h>
#include <math.h>

typedef unsigned short u16;
typedef __attribute__((ext_vector_type(8))) __bf16 bf16x8;
typedef __attribute__((ext_vector_type(4))) float f32x4;

#define LOG2E 1.44269504088896340736f
// no FIXED_M: softmax scale 2^-M cancels exactly between O and L.

__device__ inline u16 f2bf(float f){
  uint32_t u = __float_as_uint(f);
  u += 0x7FFFu + ((u >> 16) & 1u);   // round-to-nearest-even
  return (u16)(u >> 16);
}
__device__ inline float bf2f(u16 v){
  return __uint_as_float(((uint32_t)v) << 16);
}

// ---------------------------------------------------------------------------
// Kernel C: W[768][64] x3 (fp32) -> wtf in EXACT MFMA B-fragment order.
// Folds (1/8)*log2(e) into Wq so scores are in log2 domain.
// ---------------------------------------------------------------------------
__global__ __launch_bounds__(256) void wt_kernel(const float* __restrict__ Wq,
                                                 const float* __restrict__ Wk,
                                                 const float* __restrict__ Wv,
                                                 u16* __restrict__ wtf){
  int idx = blockIdx.x * 256 + threadIdx.x;
  if (idx >= 192 * 768) return;
  int n = idx / 768, c = idx - n * 768;
  int h = n & 63;
  const float* W = (n < 64) ? Wq : ((n < 128) ? Wk : Wv);
  float v = W[c * 64 + h];
  if (n < 64) v *= 0.125f * LOG2E;
  int f = n >> 4, n16 = n & 15;
  int kstep = c >> 5, quad = (c >> 3) & 3, j = c & 7;
  wtf[(size_t)((f * 24 + kstep) * 64 + quad * 16 + n16) * 8 + j] = f2bf(v);
}

// ---------------------------------------------------------------------------
// Kernel A v6: projection GEMM, M=16384, N=192, K=768. 1024 blocks x 256 thr.
// BM=16 (24KB LDS, 4 blocks/CU), waves split N (3 frags each), chunked
// pipelined staging (4 chunks of 6 k-steps, loads fly over compute).
// Epilogue via LDS -> all global stores coalesced 16B/lane.
// ksf: [b][kt][f][half][lane(quad,n16)][j] = K[kt*64+f*16+n16][half*32+quad*8+j]
// vtf: [b][kt][f][half][lane(quad,n16)][j] = V[kt*64+half*32+quad*8+j][f*16+n16]
// ---------------------------------------------------------------------------
__global__ __launch_bounds__(256) void proj_kernel(const float* __restrict__ x,
                                                   const u16* __restrict__ wtf,
                                                   u16* __restrict__ qs,
                                                   u16* __restrict__ ksf,
                                                   u16* __restrict__ vtf){
  __shared__ u16 At[24 * 64 * 8];   // 24KB; reused as epilogue buffers
  const int tid = threadIdx.x;
  const int w = tid >> 6, lane = tid & 63;
  const int n16 = lane & 15, quad = lane >> 4;
  const int rt = blockIdx.x * 16;
  const float* xb = x + (size_t)rt * 768;

  float4 tr0, tr1, tr2;
#define LOADR(c) {                                                           \
    int jj0 = tid,       r0 = jj0 / 48, q0 = jj0 - r0 * 48;                  \
    int jj1 = 256 + tid, r1 = jj1 / 48, q1 = jj1 - r1 * 48;                  \
    int jj2 = 512 + tid, r2 = jj2 / 48, q2 = jj2 - r2 * 48;                  \
    tr0 = *(const float4*)(xb + ((size_t)r0 * 192 + (c) * 48 + q0) * 4);     \
    tr1 = *(const float4*)(xb + ((size_t)r1 * 192 + (c) * 48 + q1) * 4);     \
    tr2 = *(const float4*)(xb + ((size_t)r2 * 192 + (c) * 48 + q2) * 4);     \
  }
#define WR1(c, jj, t) {                                                      \
    int rr = (jj) / 48, ql = (jj) - rr * 48;                                 \
    int ksn = (c) * 6 + (ql >> 3), qd = (ql >> 1) & 3, j0 = (ql & 1) * 4;    \
    int idx = ((ksn * 64 + qd * 16 + rr) * 8 + j0) ^ ((ksn & 7) << 3);       \
    union { ushort4 s; u16 e[4]; } pk;                                       \
    pk.e[0] = f2bf(t.x); pk.e[1] = f2bf(t.y);                                \
    pk.e[2] = f2bf(t.z); pk.e[3] = f2bf(t.w);                                \
    *(ushort4*)&At[idx] = pk.s;                                              \
  }
#define WRITES(c) { WR1(c, tid, tr0); WR1(c, 256 + tid, tr1); WR1(c, 512 + tid, tr2); }
#define COMPUTE(c) {                                                         \
    _Pragma("unroll") for (int kk = 0; kk < 6; ++kk){                        \
      int kst = (c) * 6 + kk;                                                \
      int sw = (kst & 7) << 3;                                               \
      bf16x8 a = *(const bf16x8*)&At[((kst * 64 + lane) * 8) ^ sw];          \
      _Pragma("unroll") for (int j = 0; j < 3; ++j){                         \
        bf16x8 bfr = *(const bf16x8*)(wtf + (size_t)(((3 * w + j) * 24 + kst) * 64 + lane) * 8); \
        acc[j] = __builtin_amdgcn_mfma_f32_16x16x32_bf16(a, bfr, acc[j], 0, 0, 0); \
      }                                                                      \
    }                                                                        \
  }

  const f32x4 fz = {0.f, 0.f, 0.f, 0.f};
  f32x4 acc[3];
#pragma unroll
  for (int j = 0; j < 3; ++j) acc[j] = fz;

  const int ch0 = blockIdx.x & 3;          // rotation staggers block phases
  const int ch1 = (ch0 + 1) & 3, ch2 = (ch0 + 2) & 3, ch3 = (ch0 + 3) & 3;

  LOADR(ch0); WRITES(ch0);
  __syncthreads();
  LOADR(ch1);            // flies over COMPUTE(ch0)
  COMPUTE(ch0);
  WRITES(ch1);
  __syncthreads();
  LOADR(ch2);
  COMPUTE(ch1);
  WRITES(ch2);
  __syncthreads();
  LOADR(ch3);
  COMPUTE(ch2);
  WRITES(ch3);
  __syncthreads();
  COMPUTE(ch3);
  __syncthreads();       // all waves done reading At -> safe to reuse
#undef LOADR
#undef WR1
#undef WRITES
#undef COMPUTE

  // C -> LDS transpose: EQ @0 [16][72], EK @1152 [16][72], EV @2304 [64][24]
#pragma unroll
  for (int j = 0; j < 3; ++j){
    const int F = 3 * w + j;
    const int s = F >> 2, c0 = (F & 3) * 16;
#pragma unroll
    for (int r = 0; r < 4; ++r){
      u16 val = f2bf(acc[j][r]);
      int row = quad * 4 + r;
      if (s < 2) At[s * 1152 + row * 72 + c0 + n16] = val;
      else       At[2304 + (c0 + n16) * 24 + row]   = val;
    }
  }
  __syncthreads();

  const int bb = rt >> 12, t0 = rt & 4095;
  const int kt = t0 >> 6;
  const int fk = (t0 >> 4) & 3;
  const int half0 = (t0 >> 5) & 1;
  const int qhalf = (t0 >> 4) & 1;
  if (tid < 128){
    int row = tid >> 3, hc = tid & 7;
    uint4 qv = *(const uint4*)&At[row * 72 + hc * 8];
    *(uint4*)(qs + (size_t)(rt + row) * 64 + hc * 8) = qv;
  } else {
    int tt = tid - 128;
    int half = tt >> 6, l2 = tt & 63;
    int nn = l2 & 15, qq = l2 >> 4;
    uint4 kv = *(const uint4*)&At[1152 + nn * 72 + half * 32 + qq * 8];
    size_t off = ((((size_t)(bb * 64 + kt) * 4 + fk) * 2 + half) * 64 + l2) * 8;
    *(uint4*)(ksf + off) = kv;
  }
  if (tid < 128){
    int f = tid >> 5, idx5 = tid & 31;
    int qsel = idx5 >> 4, nn = idx5 & 15;
    int h = f * 16 + nn;
    uint4 vv = *(const uint4*)&At[2304 + h * 24 + qsel * 8];
    int lane2 = (2 * qhalf + qsel) * 16 + nn;
    size_t off = ((((size_t)(bb * 64 + kt) * 4 + f) * 2 + half0) * 64 + lane2) * 8;
    *(uint4*)(vtf + off) = vv;
  }
}

// ---------------------------------------------------------------------------
// Kernel B v12: split-K causal flash (v10 body: QBLK=128, dense balanced
// grid, T14 prefetch). v12: LDS cut 34816 -> 32768 B (Ps stride 72 -> 64
// with XOR col swizzle col^((row&7)<<3); conflict-neutral, b128 reads stay
// 16B-aligned contiguous) + __launch_bounds__(256,5) -> 5 blocks/CU ->
// capacity 1280 >= 1088: ALL blocks co-resident, single scheduling round
// (previously 4/CU = 1024 < 1088 forced a 64-block straggler round).
// ---------------------------------------------------------------------------
__global__ __launch_bounds__(256, 5) void flash_part(const u16* __restrict__ qs,
                                                     const u16* __restrict__ ksf,
                                                     const u16* __restrict__ vtf,
                                                     u16* __restrict__ Opart,
                                                     float* __restrict__ ml){
  const int gid = blockIdx.x;
  int b, qt, ck, nt;
  if (gid < 1024){                       // nt=4 class
    b = gid >> 8;
    int r = gid & 255;
    int m = (int)sqrtf((float)r);
    if (m * m > r) --m;
    if ((m + 1) * (m + 1) <= r) ++m;
    int d = r - m * m;
    if (d < m){ qt = 2 * m;     ck = d;     }
    else      { qt = 2 * m + 1; ck = d - m; }
    nt = 4;
  } else {                               // nt=2 class (qt even, last chunk)
    int t = gid - 1024;
    b = t >> 4;
    int m = t & 15;
    qt = 2 * m; ck = m; nt = 2;
  }
  const int kt0 = ck * 4;

  __shared__ u16 Kb[4096];               // 8KB, frag-linear
  __shared__ u16 Vb[4096];               // 8KB
  __shared__ u16 Ps[128 * 64];           // 16KB, XOR-swizzled -> 32KB total
  const int tid = threadIdx.x;
  const int w = tid >> 6, lane = tid & 63;
  const int n16 = lane & 15, quad = lane >> 4;

  const u16* qb  = qs  + (size_t)b * 262144;
  const u16* kpg = ksf + (size_t)b * 262144 + (size_t)kt0 * 4096;
  const u16* vpg = vtf + (size_t)b * 262144 + (size_t)kt0 * 4096;

  // Q frags: qA[m][kh]
  bf16x8 qA[2][2];
#pragma unroll
  for (int m = 0; m < 2; ++m){
    const size_t qrow = (size_t)(qt * 128 + w * 32 + m * 16 + n16) * 64;
    qA[m][0] = *(const bf16x8*)(qb + qrow + quad * 8);
    qA[m][1] = *(const bf16x8*)(qb + qrow + 32 + quad * 8);
  }

  const f32x4 fz = {0.f, 0.f, 0.f, 0.f};
  f32x4 O[2][4];
  float rs[2][4];
#pragma unroll
  for (int m = 0; m < 2; ++m)
#pragma unroll
    for (int f = 0; f < 4; ++f){ O[m][f] = fz; rs[m][f] = 0.f; }

  // T14 staging registers: thread tid owns bytes [tid*32, +32) of each tile.
  uint4 rk0, rk1, rv0, rv1;
#define LOADR(ti)                                                            \
  {                                                                          \
    const u16* kg = kpg + (size_t)(ti) * 4096 + tid * 16;                    \
    const u16* vg = vpg + (size_t)(ti) * 4096 + tid * 16;                    \
    rk0 = *(const uint4*)kg;  rk1 = *(const uint4*)(kg + 8);                 \
    rv0 = *(const uint4*)vg;  rv1 = *(const uint4*)(vg + 8);                 \
  }
#define WRITES()                                                             \
  {                                                                          \
    *(uint4*)&Kb[tid * 16] = rk0;  *(uint4*)&Kb[tid * 16 + 8] = rk1;         \
    *(uint4*)&Vb[tid * 16] = rv0;  *(uint4*)&Vb[tid * 16 + 8] = rv1;         \
  }

  LOADR(0);
  WRITES();
  __syncthreads();                       // tile 0 ready

  for (int it = 0; it < nt; ++it){
    const int kt = kt0 + it;
    if (it + 1 < nt) LOADR(it + 1);      // flies over this iter's compute

    f32x4 S[2][4];
#pragma unroll
    for (int f = 0; f < 4; ++f){
      bf16x8 k0 = *(const bf16x8*)&Kb[(f * 2 + 0) * 512 + lane * 8];
      bf16x8 k1 = *(const bf16x8*)&Kb[(f * 2 + 1) * 512 + lane * 8];
#pragma unroll
      for (int m = 0; m < 2; ++m){
        f32x4 s = fz;
        s = __builtin_amdgcn_mfma_f32_16x16x32_bf16(qA[m][0], k0, s, 0, 0, 0);
        s = __builtin_amdgcn_mfma_f32_16x16x32_bf16(qA[m][1], k1, s, 0, 0, 0);
        S[m][f] = s;
      }
    }

    if (kt >= 2 * qt){
#pragma unroll
      for (int m = 0; m < 2; ++m)
#pragma unroll
        for (int f = 0; f < 4; ++f)
#pragma unroll
          for (int r = 0; r < 4; ++r){
            int col = kt * 64 + f * 16 + n16;
            int row = qt * 128 + w * 32 + m * 16 + quad * 4 + r;
            if (col > row) S[m][f][r] = -1e30f;
          }
    }

#pragma unroll
    for (int m = 0; m < 2; ++m)
#pragma unroll
      for (int f = 0; f < 4; ++f)
#pragma unroll
        for (int r = 0; r < 4; ++r){
          float p = __builtin_amdgcn_exp2f(S[m][f][r]);
          S[m][f][r] = p;
          rs[m][r] += p;
        }

    // P: C-layout -> swizzled LDS -> A-layout (intra-wave, no barrier)
    // store (row, col) at Ps[row*64 + (col ^ ((row&7)<<3))]
#pragma unroll
    for (int m = 0; m < 2; ++m)
#pragma unroll
      for (int f = 0; f < 4; ++f)
#pragma unroll
        for (int r = 0; r < 4; ++r){
          int row = w * 32 + m * 16 + quad * 4 + r;
          Ps[row * 64 + ((f * 16 + n16) ^ ((row & 7) << 3))] = f2bf(S[m][f][r]);
        }
    bf16x8 pA[2][2];
#pragma unroll
    for (int m = 0; m < 2; ++m){
      int rrow = w * 32 + m * 16 + n16;
      int sw2 = (rrow & 7) << 3;
      pA[m][0] = *(const bf16x8*)&Ps[rrow * 64 + ((quad * 8) ^ sw2)];
      pA[m][1] = *(const bf16x8*)&Ps[rrow * 64 + ((32 + quad * 8) ^ sw2)];
    }

#pragma unroll
    for (int f = 0; f < 4; ++f){
      bf16x8 v0 = *(const bf16x8*)&Vb[(f * 2 + 0) * 512 + lane * 8];
      bf16x8 v1 = *(const bf16x8*)&Vb[(f * 2 + 1) * 512 + lane * 8];
#pragma unroll
      for (int m = 0; m < 2; ++m){
        O[m][f] = __builtin_amdgcn_mfma_f32_16x16x32_bf16(pA[m][0], v0, O[m][f], 0, 0, 0);
        O[m][f] = __builtin_amdgcn_mfma_f32_16x16x32_bf16(pA[m][1], v1, O[m][f], 0, 0, 0);
      }
    }

    if (it + 1 < nt){
      __syncthreads();                   // all waves done reading tile it
      WRITES();                          // staged regs -> LDS (tile it+1)
      __syncthreads();                   // tile it+1 visible
    }
  }
#undef LOADR
#undef WRITES

  // one-time row-sum reduction across the 16 n16 lanes
#pragma unroll
  for (int m = 0; m < 2; ++m)
#pragma unroll
    for (int r = 0; r < 4; ++r){
#pragma unroll
      for (int off = 1; off < 16; off <<= 1)
        rs[m][r] += __shfl_xor(rs[m][r], off, 16);
    }

  // epilogue: unnormalized partial O (bf16) + l per row, indexed by dense gid
  const size_t oidx = (size_t)gid * 8192;
#pragma unroll
  for (int m = 0; m < 2; ++m)
#pragma unroll
    for (int f = 0; f < 4; ++f)
#pragma unroll
      for (int r = 0; r < 4; ++r){
        int row_local = w * 32 + m * 16 + quad * 4 + r;
        Opart[oidx + (size_t)row_local * 64 + f * 16 + n16] = f2bf(O[m][f][r]);
      }
  if (n16 == 0){
    float* lp = ml + (size_t)gid * 128;
#pragma unroll
    for (int m = 0; m < 2; ++m)
#pragma unroll
      for (int r = 0; r < 4; ++r)
        lp[w * 32 + m * 16 + quad * 4 + r] = rs[m][r];
  }
}

// ---------------------------------------------------------------------------
// Kernel D v8: combine partials from the dense grid.
// (b,qt): nt4 partials at b*256 + F(qt) + j (j < full(qt)); if qt even, one
// nt2 partial at 1024 + b*16 + qt/2. F(2m)=m^2, F(2m+1)=m^2+m.
// out = sum O / sum l.
// ---------------------------------------------------------------------------
__global__ __launch_bounds__(256) void combine_kernel(const u16* __restrict__ Opart,
                                                      const float* __restrict__ ml,
                                                      float* __restrict__ out){
  const int gid = blockIdx.x * 256 + threadIdx.x;   // 262144 threads
  const int bq = gid >> 11;                         // b*32+qt
  const int rem = (gid & 2047) * 4;                 // elem within 128x64 tile
  const int row = rem >> 6;
  const int b = bq >> 5, qt = bq & 31;
  const int m = qt >> 1;
  const int nc4 = (qt & 1) ? (m + 1) : m;
  const int F = (qt & 1) ? (m * m + m) : (m * m);

  float L = 0.f;
  float a0 = 0.f, a1 = 0.f, a2 = 0.f, a3 = 0.f;
  for (int j = 0; j < nc4; ++j){
    int p = b * 256 + F + j;
    L += ml[(size_t)p * 128 + row];
    const u16* q = Opart + (size_t)p * 8192 + rem;
    uint2 d = *(const uint2*)q;
    a0 += bf2f((u16)(d.x & 0xffffu));
    a1 += bf2f((u16)(d.x >> 16));
    a2 += bf2f((u16)(d.y & 0xffffu));
    a3 += bf2f((u16)(d.y >> 16));
  }
  if (!(qt & 1)){
    int p = 1024 + b * 16 + m;
    L += ml[(size_t)p * 128 + row];
    const u16* q = Opart + (size_t)p * 8192 + rem;
    uint2 d = *(const uint2*)q;
    a0 += bf2f((u16)(d.x & 0xffffu));
    a1 += bf2f((u16)(d.x >> 16));
    a2 += bf2f((u16)(d.y & 0xffffu));
    a3 += bf2f((u16)(d.y >> 16));
  }
  const float invL = 1.0f / L;
  float4 v = {a0 * invL, a1 * invL, a2 * invL, a3 * invL};
  *(float4*)(out + (size_t)gid * 4) = v;
}

// ---------------------------------------------------------------------------
extern "C" void kernel_launch(void* const* d_in, const int* in_sizes, int n_in,
                              void* d_out, int out_size, void* d_ws, size_t ws_size,
                              hipStream_t stream){
  const float* x  = (const float*)d_in[0];
  const float* Wq = (const float*)d_in[1];
  const float* Wk = (const float*)d_in[2];
  const float* Wv = (const float*)d_in[3];
  float* out = (float*)d_out;

  // ws (u16 elems): qs|ksf|vtf (each 16384*64) | wtf (192*768)
  //                 | Opart (1088*8192) | ml (1088*128 f32)  ~25 MB
  u16* qs  = (u16*)d_ws;
  u16* ksf = qs  + (size_t)16384 * 64;
  u16* vtf = ksf + (size_t)16384 * 64;
  u16* wtf = vtf + (size_t)16384 * 64;
  u16* Opart = wtf + (size_t)192 * 768;
  float* ml = (float*)(Opart + (size_t)1088 * 8192);

  wt_kernel<<<576, 256, 0, stream>>>(Wq, Wk, Wv, wtf);
  proj_kernel<<<1024, 256, 0, stream>>>(x, wtf, qs, ksf, vtf);
  flash_part<<<1088, 256, 0, stream>>>(qs, ksf, vtf, Opart, ml);
  combine_kernel<<<1024, 256, 0, stream>>>(Opart, ml, out);
}

// Round 16
// 129.247 us; speedup vs baseline: 2.6181x; 1.5642x over previous
//
#include <hip/hip_runtime.h>
#include <hip/hip_bf16.h>
#include <stdint.h>
#include <math.h>

typedef unsigned short u16;
typedef __attribute__((ext_vector_type(8))) __bf16 bf16x8;
typedef __attribute__((ext_vector_type(4))) float f32x4;

#define LOG2E 1.44269504088896340736f
// no FIXED_M: softmax scale 2^-M cancels exactly between O and L.

__device__ inline u16 f2bf(float f){
  uint32_t u = __float_as_uint(f);
  u += 0x7FFFu + ((u >> 16) & 1u);   // round-to-nearest-even
  return (u16)(u >> 16);
}
__device__ inline float bf2f(u16 v){
  return __uint_as_float(((uint32_t)v) << 16);
}

// ---------------------------------------------------------------------------
// Kernel C: W[768][64] x3 (fp32) -> wtf in EXACT MFMA B-fragment order.
// Folds (1/8)*log2(e) into Wq so scores are in log2 domain.
// ---------------------------------------------------------------------------
__global__ __launch_bounds__(256) void wt_kernel(const float* __restrict__ Wq,
                                                 const float* __restrict__ Wk,
                                                 const float* __restrict__ Wv,
                                                 u16* __restrict__ wtf){
  int idx = blockIdx.x * 256 + threadIdx.x;
  if (idx >= 192 * 768) return;
  int n = idx / 768, c = idx - n * 768;
  int h = n & 63;
  const float* W = (n < 64) ? Wq : ((n < 128) ? Wk : Wv);
  float v = W[c * 64 + h];
  if (n < 64) v *= 0.125f * LOG2E;
  int f = n >> 4, n16 = n & 15;
  int kstep = c >> 5, quad = (c >> 3) & 3, j = c & 7;
  wtf[(size_t)((f * 24 + kstep) * 64 + quad * 16 + n16) * 8 + j] = f2bf(v);
}

// ---------------------------------------------------------------------------
// Kernel A v6: projection GEMM, M=16384, N=192, K=768. 1024 blocks x 256 thr.
// BM=16 (24KB LDS, 4 blocks/CU), waves split N (3 frags each), chunked
// pipelined staging (4 chunks of 6 k-steps, loads fly over compute).
// Epilogue via LDS -> all global stores coalesced 16B/lane.
// ksf: [b][kt][f][half][lane(quad,n16)][j] = K[kt*64+f*16+n16][half*32+quad*8+j]
// vtf: [b][kt][f][half][lane(quad,n16)][j] = V[kt*64+half*32+quad*8+j][f*16+n16]
// ---------------------------------------------------------------------------
__global__ __launch_bounds__(256) void proj_kernel(const float* __restrict__ x,
                                                   const u16* __restrict__ wtf,
                                                   u16* __restrict__ qs,
                                                   u16* __restrict__ ksf,
                                                   u16* __restrict__ vtf){
  __shared__ u16 At[24 * 64 * 8];   // 24KB; reused as epilogue buffers
  const int tid = threadIdx.x;
  const int w = tid >> 6, lane = tid & 63;
  const int n16 = lane & 15, quad = lane >> 4;
  const int rt = blockIdx.x * 16;
  const float* xb = x + (size_t)rt * 768;

  float4 tr0, tr1, tr2;
#define LOADR(c) {                                                           \
    int jj0 = tid,       r0 = jj0 / 48, q0 = jj0 - r0 * 48;                  \
    int jj1 = 256 + tid, r1 = jj1 / 48, q1 = jj1 - r1 * 48;                  \
    int jj2 = 512 + tid, r2 = jj2 / 48, q2 = jj2 - r2 * 48;                  \
    tr0 = *(const float4*)(xb + ((size_t)r0 * 192 + (c) * 48 + q0) * 4);     \
    tr1 = *(const float4*)(xb + ((size_t)r1 * 192 + (c) * 48 + q1) * 4);     \
    tr2 = *(const float4*)(xb + ((size_t)r2 * 192 + (c) * 48 + q2) * 4);     \
  }
#define WR1(c, jj, t) {                                                      \
    int rr = (jj) / 48, ql = (jj) - rr * 48;                                 \
    int ksn = (c) * 6 + (ql >> 3), qd = (ql >> 1) & 3, j0 = (ql & 1) * 4;    \
    int idx = ((ksn * 64 + qd * 16 + rr) * 8 + j0) ^ ((ksn & 7) << 3);       \
    union { ushort4 s; u16 e[4]; } pk;                                       \
    pk.e[0] = f2bf(t.x); pk.e[1] = f2bf(t.y);                                \
    pk.e[2] = f2bf(t.z); pk.e[3] = f2bf(t.w);                                \
    *(ushort4*)&At[idx] = pk.s;                                              \
  }
#define WRITES(c) { WR1(c, tid, tr0); WR1(c, 256 + tid, tr1); WR1(c, 512 + tid, tr2); }
#define COMPUTE(c) {                                                         \
    _Pragma("unroll") for (int kk = 0; kk < 6; ++kk){                        \
      int kst = (c) * 6 + kk;                                                \
      int sw = (kst & 7) << 3;                                               \
      bf16x8 a = *(const bf16x8*)&At[((kst * 64 + lane) * 8) ^ sw];          \
      _Pragma("unroll") for (int j = 0; j < 3; ++j){                         \
        bf16x8 bfr = *(const bf16x8*)(wtf + (size_t)(((3 * w + j) * 24 + kst) * 64 + lane) * 8); \
        acc[j] = __builtin_amdgcn_mfma_f32_16x16x32_bf16(a, bfr, acc[j], 0, 0, 0); \
      }                                                                      \
    }                                                                        \
  }

  const f32x4 fz = {0.f, 0.f, 0.f, 0.f};
  f32x4 acc[3];
#pragma unroll
  for (int j = 0; j < 3; ++j) acc[j] = fz;

  const int ch0 = blockIdx.x & 3;          // rotation staggers block phases
  const int ch1 = (ch0 + 1) & 3, ch2 = (ch0 + 2) & 3, ch3 = (ch0 + 3) & 3;

  LOADR(ch0); WRITES(ch0);
  __syncthreads();
  LOADR(ch1);            // flies over COMPUTE(ch0)
  COMPUTE(ch0);
  WRITES(ch1);
  __syncthreads();
  LOADR(ch2);
  COMPUTE(ch1);
  WRITES(ch2);
  __syncthreads();
  LOADR(ch3);
  COMPUTE(ch2);
  WRITES(ch3);
  __syncthreads();
  COMPUTE(ch3);
  __syncthreads();       // all waves done reading At -> safe to reuse
#undef LOADR
#undef WR1
#undef WRITES
#undef COMPUTE

  // C -> LDS transpose: EQ @0 [16][72], EK @1152 [16][72], EV @2304 [64][24]
#pragma unroll
  for (int j = 0; j < 3; ++j){
    const int F = 3 * w + j;
    const int s = F >> 2, c0 = (F & 3) * 16;
#pragma unroll
    for (int r = 0; r < 4; ++r){
      u16 val = f2bf(acc[j][r]);
      int row = quad * 4 + r;
      if (s < 2) At[s * 1152 + row * 72 + c0 + n16] = val;
      else       At[2304 + (c0 + n16) * 24 + row]   = val;
    }
  }
  __syncthreads();

  const int bb = rt >> 12, t0 = rt & 4095;
  const int kt = t0 >> 6;
  const int fk = (t0 >> 4) & 3;
  const int half0 = (t0 >> 5) & 1;
  const int qhalf = (t0 >> 4) & 1;
  if (tid < 128){
    int row = tid >> 3, hc = tid & 7;
    uint4 qv = *(const uint4*)&At[row * 72 + hc * 8];
    *(uint4*)(qs + (size_t)(rt + row) * 64 + hc * 8) = qv;
  } else {
    int tt = tid - 128;
    int half = tt >> 6, l2 = tt & 63;
    int nn = l2 & 15, qq = l2 >> 4;
    uint4 kv = *(const uint4*)&At[1152 + nn * 72 + half * 32 + qq * 8];
    size_t off = ((((size_t)(bb * 64 + kt) * 4 + fk) * 2 + half) * 64 + l2) * 8;
    *(uint4*)(ksf + off) = kv;
  }
  if (tid < 128){
    int f = tid >> 5, idx5 = tid & 31;
    int qsel = idx5 >> 4, nn = idx5 & 15;
    int h = f * 16 + nn;
    uint4 vv = *(const uint4*)&At[2304 + h * 24 + qsel * 8];
    int lane2 = (2 * qhalf + qsel) * 16 + nn;
    size_t off = ((((size_t)(bb * 64 + kt) * 4 + f) * 2 + half0) * 64 + lane2) * 8;
    *(uint4*)(vtf + off) = vv;
  }
}

// ---------------------------------------------------------------------------
// Kernel B v13: split-K causal flash (v10 body: QBLK=128, dense balanced
// grid, T14 prefetch). LDS = exactly 32768 B (Ps stride 64 + XOR swizzle,
// correctness-verified in r15) -> LDS permits 5 blocks/CU. NO launch-bounds
// minimum: r15 proved forcing 5 waves/EU collapses the allocator to 48 VGPR
// and spills everything (FETCH+WRITE 27->302 MB). Natural allocation is
// ~100 VGPR (r14) <= 102 = 512/5, so the 5th block can engage on its own;
// worst case we get r12's 4/CU with no downside.
// ---------------------------------------------------------------------------
__global__ __launch_bounds__(256) void flash_part(const u16* __restrict__ qs,
                                                  const u16* __restrict__ ksf,
                                                  const u16* __restrict__ vtf,
                                                  u16* __restrict__ Opart,
                                                  float* __restrict__ ml){
  const int gid = blockIdx.x;
  int b, qt, ck, nt;
  if (gid < 1024){                       // nt=4 class
    b = gid >> 8;
    int r = gid & 255;
    int m = (int)sqrtf((float)r);
    if (m * m > r) --m;
    if ((m + 1) * (m + 1) <= r) ++m;
    int d = r - m * m;
    if (d < m){ qt = 2 * m;     ck = d;     }
    else      { qt = 2 * m + 1; ck = d - m; }
    nt = 4;
  } else {                               // nt=2 class (qt even, last chunk)
    int t = gid - 1024;
    b = t >> 4;
    int m = t & 15;
    qt = 2 * m; ck = m; nt = 2;
  }
  const int kt0 = ck * 4;

  __shared__ u16 Kb[4096];               // 8KB, frag-linear
  __shared__ u16 Vb[4096];               // 8KB
  __shared__ u16 Ps[128 * 64];           // 16KB, XOR-swizzled -> 32KB total
  const int tid = threadIdx.x;
  const int w = tid >> 6, lane = tid & 63;
  const int n16 = lane & 15, quad = lane >> 4;

  const u16* qb  = qs  + (size_t)b * 262144;
  const u16* kpg = ksf + (size_t)b * 262144 + (size_t)kt0 * 4096;
  const u16* vpg = vtf + (size_t)b * 262144 + (size_t)kt0 * 4096;

  // Q frags: qA[m][kh]
  bf16x8 qA[2][2];
#pragma unroll
  for (int m = 0; m < 2; ++m){
    const size_t qrow = (size_t)(qt * 128 + w * 32 + m * 16 + n16) * 64;
    qA[m][0] = *(const bf16x8*)(qb + qrow + quad * 8);
    qA[m][1] = *(const bf16x8*)(qb + qrow + 32 + quad * 8);
  }

  const f32x4 fz = {0.f, 0.f, 0.f, 0.f};
  f32x4 O[2][4];
  float rs[2][4];
#pragma unroll
  for (int m = 0; m < 2; ++m)
#pragma unroll
    for (int f = 0; f < 4; ++f){ O[m][f] = fz; rs[m][f] = 0.f; }

  // T14 staging registers: thread tid owns bytes [tid*32, +32) of each tile.
  uint4 rk0, rk1, rv0, rv1;
#define LOADR(ti)                                                            \
  {                                                                          \
    const u16* kg = kpg + (size_t)(ti) * 4096 + tid * 16;                    \
    const u16* vg = vpg + (size_t)(ti) * 4096 + tid * 16;                    \
    rk0 = *(const uint4*)kg;  rk1 = *(const uint4*)(kg + 8);                 \
    rv0 = *(const uint4*)vg;  rv1 = *(const uint4*)(vg + 8);                 \
  }
#define WRITES()                                                             \
  {                                                                          \
    *(uint4*)&Kb[tid * 16] = rk0;  *(uint4*)&Kb[tid * 16 + 8] = rk1;         \
    *(uint4*)&Vb[tid * 16] = rv0;  *(uint4*)&Vb[tid * 16 + 8] = rv1;         \
  }

  LOADR(0);
  WRITES();
  __syncthreads();                       // tile 0 ready

  for (int it = 0; it < nt; ++it){
    const int kt = kt0 + it;
    if (it + 1 < nt) LOADR(it + 1);      // flies over this iter's compute

    f32x4 S[2][4];
#pragma unroll
    for (int f = 0; f < 4; ++f){
      bf16x8 k0 = *(const bf16x8*)&Kb[(f * 2 + 0) * 512 + lane * 8];
      bf16x8 k1 = *(const bf16x8*)&Kb[(f * 2 + 1) * 512 + lane * 8];
#pragma unroll
      for (int m = 0; m < 2; ++m){
        f32x4 s = fz;
        s = __builtin_amdgcn_mfma_f32_16x16x32_bf16(qA[m][0], k0, s, 0, 0, 0);
        s = __builtin_amdgcn_mfma_f32_16x16x32_bf16(qA[m][1], k1, s, 0, 0, 0);
        S[m][f] = s;
      }
    }

    if (kt >= 2 * qt){
#pragma unroll
      for (int m = 0; m < 2; ++m)
#pragma unroll
        for (int f = 0; f < 4; ++f)
#pragma unroll
          for (int r = 0; r < 4; ++r){
            int col = kt * 64 + f * 16 + n16;
            int row = qt * 128 + w * 32 + m * 16 + quad * 4 + r;
            if (col > row) S[m][f][r] = -1e30f;
          }
    }

#pragma unroll
    for (int m = 0; m < 2; ++m)
#pragma unroll
      for (int f = 0; f < 4; ++f)
#pragma unroll
        for (int r = 0; r < 4; ++r){
          float p = __builtin_amdgcn_exp2f(S[m][f][r]);
          S[m][f][r] = p;
          rs[m][r] += p;
        }

    // P: C-layout -> swizzled LDS -> A-layout (intra-wave, no barrier)
    // store (row, col) at Ps[row*64 + (col ^ ((row&7)<<3))]
#pragma unroll
    for (int m = 0; m < 2; ++m)
#pragma unroll
      for (int f = 0; f < 4; ++f)
#pragma unroll
        for (int r = 0; r < 4; ++r){
          int row = w * 32 + m * 16 + quad * 4 + r;
          Ps[row * 64 + ((f * 16 + n16) ^ ((row & 7) << 3))] = f2bf(S[m][f][r]);
        }
    bf16x8 pA[2][2];
#pragma unroll
    for (int m = 0; m < 2; ++m){
      int rrow = w * 32 + m * 16 + n16;
      int sw2 = (rrow & 7) << 3;
      pA[m][0] = *(const bf16x8*)&Ps[rrow * 64 + ((quad * 8) ^ sw2)];
      pA[m][1] = *(const bf16x8*)&Ps[rrow * 64 + ((32 + quad * 8) ^ sw2)];
    }

#pragma unroll
    for (int f = 0; f < 4; ++f){
      bf16x8 v0 = *(const bf16x8*)&Vb[(f * 2 + 0) * 512 + lane * 8];
      bf16x8 v1 = *(const bf16x8*)&Vb[(f * 2 + 1) * 512 + lane * 8];
#pragma unroll
      for (int m = 0; m < 2; ++m){
        O[m][f] = __builtin_amdgcn_mfma_f32_16x16x32_bf16(pA[m][0], v0, O[m][f], 0, 0, 0);
        O[m][f] = __builtin_amdgcn_mfma_f32_16x16x32_bf16(pA[m][1], v1, O[m][f], 0, 0, 0);
      }
    }

    if (it + 1 < nt){
      __syncthreads();                   // all waves done reading tile it
      WRITES();                          // staged regs -> LDS (tile it+1)
      __syncthreads();                   // tile it+1 visible
    }
  }
#undef LOADR
#undef WRITES

  // one-time row-sum reduction across the 16 n16 lanes
#pragma unroll
  for (int m = 0; m < 2; ++m)
#pragma unroll
    for (int r = 0; r < 4; ++r){
#pragma unroll
      for (int off = 1; off < 16; off <<= 1)
        rs[m][r] += __shfl_xor(rs[m][r], off, 16);
    }

  // epilogue: unnormalized partial O (bf16) + l per row, indexed by dense gid
  const size_t oidx = (size_t)gid * 8192;
#pragma unroll
  for (int m = 0; m < 2; ++m)
#pragma unroll
    for (int f = 0; f < 4; ++f)
#pragma unroll
      for (int r = 0; r < 4; ++r){
        int row_local = w * 32 + m * 16 + quad * 4 + r;
        Opart[oidx + (size_t)row_local * 64 + f * 16 + n16] = f2bf(O[m][f][r]);
      }
  if (n16 == 0){
    float* lp = ml + (size_t)gid * 128;
#pragma unroll
    for (int m = 0; m < 2; ++m)
#pragma unroll
      for (int r = 0; r < 4; ++r)
        lp[w * 32 + m * 16 + quad * 4 + r] = rs[m][r];
  }
}

// ---------------------------------------------------------------------------
// Kernel D v8: combine partials from the dense grid.
// (b,qt): nt4 partials at b*256 + F(qt) + j (j < full(qt)); if qt even, one
// nt2 partial at 1024 + b*16 + qt/2. F(2m)=m^2, F(2m+1)=m^2+m.
// out = sum O / sum l.
// ---------------------------------------------------------------------------
__global__ __launch_bounds__(256) void combine_kernel(const u16* __restrict__ Opart,
                                                      const float* __restrict__ ml,
                                                      float* __restrict__ out){
  const int gid = blockIdx.x * 256 + threadIdx.x;   // 262144 threads
  const int bq = gid >> 11;                         // b*32+qt
  const int rem = (gid & 2047) * 4;                 // elem within 128x64 tile
  const int row = rem >> 6;
  const int b = bq >> 5, qt = bq & 31;
  const int m = qt >> 1;
  const int nc4 = (qt & 1) ? (m + 1) : m;
  const int F = (qt & 1) ? (m * m + m) : (m * m);

  float L = 0.f;
  float a0 = 0.f, a1 = 0.f, a2 = 0.f, a3 = 0.f;
  for (int j = 0; j < nc4; ++j){
    int p = b * 256 + F + j;
    L += ml[(size_t)p * 128 + row];
    const u16* q = Opart + (size_t)p * 8192 + rem;
    uint2 d = *(const uint2*)q;
    a0 += bf2f((u16)(d.x & 0xffffu));
    a1 += bf2f((u16)(d.x >> 16));
    a2 += bf2f((u16)(d.y & 0xffffu));
    a3 += bf2f((u16)(d.y >> 16));
  }
  if (!(qt & 1)){
    int p = 1024 + b * 16 + m;
    L += ml[(size_t)p * 128 + row];
    const u16* q = Opart + (size_t)p * 8192 + rem;
    uint2 d = *(const uint2*)q;
    a0 += bf2f((u16)(d.x & 0xffffu));
    a1 += bf2f((u16)(d.x >> 16));
    a2 += bf2f((u16)(d.y & 0xffffu));
    a3 += bf2f((u16)(d.y >> 16));
  }
  const float invL = 1.0f / L;
  float4 v = {a0 * invL, a1 * invL, a2 * invL, a3 * invL};
  *(float4*)(out + (size_t)gid * 4) = v;
}

// ---------------------------------------------------------------------------
extern "C" void kernel_launch(void* const* d_in, const int* in_sizes, int n_in,
                              void* d_out, int out_size, void* d_ws, size_t ws_size,
                              hipStream_t stream){
  const float* x  = (const float*)d_in[0];
  const float* Wq = (const float*)d_in[1];
  const float* Wk = (const float*)d_in[2];
  const float* Wv = (const float*)d_in[3];
  float* out = (float*)d_out;

  // ws (u16 elems): qs|ksf|vtf (each 16384*64) | wtf (192*768)
  //                 | Opart (1088*8192) | ml (1088*128 f32)  ~25 MB
  u16* qs  = (u16*)d_ws;
  u16* ksf = qs  + (size_t)16384 * 64;
  u16* vtf = ksf + (size_t)16384 * 64;
  u16* wtf = vtf + (size_t)16384 * 64;
  u16* Opart = wtf + (size_t)192 * 768;
  float* ml = (float*)(Opart + (size_t)1088 * 8192);

  wt_kernel<<<576, 256, 0, stream>>>(Wq, Wk, Wv, wtf);
  proj_kernel<<<1024, 256, 0, stream>>>(x, wtf, qs, ksf, vtf);
  flash_part<<<1088, 256, 0, stream>>>(qs, ksf, vtf, Opart, ml);
  combine_kernel<<<1024, 256, 0, stream>>>(Opart, ml, out);
}